// Round 14
// baseline (276.029 us; speedup 1.0000x reference)
//
#include <hip/hip_runtime.h>
#include <cstdint>
#include <cstddef>

#define B_ 8
#define N_ 10000
#define C_ 64
#define DIM_ 256
#define E_ 160000
#define ROWS_ (B_ * N_)            // 80000
#define OUT_OFF_ ((size_t)B_ * N_ * C_)  // 5,120,000

typedef unsigned short u16;
typedef unsigned int u32;
typedef __attribute__((ext_vector_type(8))) short bf16x8;
typedef __attribute__((ext_vector_type(4))) float f32x4;

__device__ __forceinline__ u16 f2bf(float f) {
    unsigned int u = __float_as_uint(f);
    unsigned int r = u + 0x7FFF + ((u >> 16) & 1);  // RNE
    return (u16)(r >> 16);
}
__device__ __forceinline__ float bf2f(u32 h) {      // low 16 bits hold bf16
    return __uint_as_float(h << 16);
}
__device__ __forceinline__ unsigned int pack2(float a, float b) {
    return (unsigned int)f2bf(a) | ((unsigned int)f2bf(b) << 16);
}
__device__ __forceinline__ float swish_f(float v, float sp) {
    float e = __expf(-v * sp);
    float s = __builtin_amdgcn_rcpf(1.0f + e);
    return v * s * (1.0f / 1.1f);
}

#define MFMA16(a, b, c) __builtin_amdgcn_mfma_f32_16x16x32_bf16(a, b, c, 0, 0, 0)

// ---- graph preprocessing -------------------------------------------------
// R14: edges chunk-sorted by src (chunk = src>>10, 10 chunks of 1024 nodes
// ~ 1 MB of gather rows each). All prop waves then sweep src-space in the
// same chunk order -> instantaneous gather working set ~1-2 MB, fits every
// XCD's 4 MB L2 (R11 measured 43% of the 164 MB gather going to HBM with
// random order: 10.2 MB source vs 4 MB L2 -> ~40% hit, matches).

__global__ void k_deg(const int* __restrict__ src, const int* __restrict__ dst,
                      const float* __restrict__ ew,
                      float* __restrict__ deg, int* __restrict__ cnt10) {
    int e = blockIdx.x * 256 + threadIdx.x;
    if (e < E_) {
        int sn = src[e], dn = dst[e];
        atomicAdd(&deg[dn], ew[e]);
        atomicAdd(&cnt10[dn * 10 + (sn >> 10)], 1);
    }
}

// scan + dis fused; also emits per-(node,chunk) cursors for sorted scatter.
__global__ void k_scan(const int* __restrict__ cnt10, const float* __restrict__ deg,
                       int* __restrict__ offs, int* __restrict__ cursor10,
                       float* __restrict__ dis) {
    __shared__ int part[1024];
    int t = threadIdx.x;
    const int CH = 10;
    int base = t * CH;
    int s = 0;
    for (int i = 0; i < CH; i++) {
        int idx = base + i;
        if (idx < N_) {
#pragma unroll
            for (int c = 0; c < 10; ++c) s += cnt10[idx * 10 + c];
        }
    }
    part[t] = s;
    __syncthreads();
    for (int off = 1; off < 1024; off <<= 1) {
        int v = 0;
        if (t >= off) v = part[t - off];
        __syncthreads();
        if (t >= off) part[t] += v;
        __syncthreads();
    }
    int run = (t > 0) ? part[t - 1] : 0;
    for (int i = 0; i < CH; i++) {
        int idx = base + i;
        if (idx < N_) {
            offs[idx] = run;
#pragma unroll
            for (int c = 0; c < 10; ++c) {
                cursor10[idx * 10 + c] = run;
                run += cnt10[idx * 10 + c];
            }
            float d = deg[idx];
            dis[idx] = d > 0.f ? rsqrtf(d) : 0.f;
        }
    }
    if (t == 1023) offs[N_] = run;
}

// scatter (chunk-sorted positions) + weight-prep merged; block-range split.
#define SCAT_BLKS_ ((E_ + 255) / 256)              // 625
__global__ void k_sp(const int* __restrict__ src, const int* __restrict__ dst,
                     const float* __restrict__ ew, const float* __restrict__ dis,
                     int* __restrict__ cursor10, int* __restrict__ ssrc,
                     float* __restrict__ sw,
                     const float* __restrict__ Wc, const float* __restrict__ W1,
                     const float* __restrict__ W2, const float* __restrict__ x,
                     u16* __restrict__ Wct, u16* __restrict__ W1t,
                     u16* __restrict__ W2t, u16* __restrict__ xg) {
    if (blockIdx.x < SCAT_BLKS_) {
        int e = blockIdx.x * 256 + threadIdx.x;
        if (e < E_) {
            int sn = src[e], dn = dst[e];
            float w = -(dis[sn] * ew[e] * dis[dn]);
            int p = atomicAdd(&cursor10[dn * 10 + (sn >> 10)], 1);
            ssrc[p] = sn;
            sw[p] = w;
        }
        return;
    }
    int i = (blockIdx.x - SCAT_BLKS_) * 256 + threadIdx.x;
    if (i < 49152) {
        int nr = i / 192, k = i % 192;
        Wct[i] = f2bf(Wc[k * 256 + nr]);
    } else if (i < 114688) {
        int j = i - 49152;
        int nr = j >> 8, k = j & 255;
        W1t[j] = f2bf(W1[k * 256 + nr]);
    } else if (i < 131072) {
        int j = i - 114688;
        int nr = j >> 8, k = j & 255;
        W2t[j] = f2bf(W2[k * 64 + nr]);
    } else {
        int j = i - 131072;
        if (j < (B_ * N_ * C_) / 4) {
            float4 v = ((const float4*)x)[j];
            int flat4 = j * 4;                 // [b][n][c] flat f32 index
            int b = flat4 / (N_ * C_);
            int rem = flat4 - b * (N_ * C_);
            int n = rem >> 6, c = rem & 63;
            uint2 pv = {pack2(v.x, v.y), pack2(v.z, v.w)};
            *(uint2*)(xg + (size_t)n * 512 + b * 64 + c) = pv;
        }
    }
}

// Batch-merged gather SpMM (R7/R8/R9). One wave per NODE; per edge one
// contiguous 1 KB row (8 batches x 64 ch), 8-deep edge pipeline. Edge list
// is now src-chunk-sorted (R14) -> L2-windowed gathers.
// Lane l owns (b=l>>3, c=(l&7)*8..+8). mode==1: O = 2*sum - xg_row.
__global__ __launch_bounds__(256) void k_prop_g(
        const u16* __restrict__ Tg, const int* __restrict__ offs,
        const int* __restrict__ ssrc, const float* __restrict__ sw,
        const u16* __restrict__ xg, u16* __restrict__ Og, int mode) {
    int w = __builtin_amdgcn_readfirstlane(threadIdx.x >> 6);
    int lane = threadIdx.x & 63;
    int n = blockIdx.x * 4 + w;
    int s = offs[n], e = offs[n + 1];
    int lo = lane * 8;
    float sum[8] = {};
    int j = s;
    for (; j < e && (j & 3); ++j) {
        int idx = ssrc[j];
        float wv = sw[j];
        bf16x8 v = *(const bf16x8*)(Tg + (size_t)idx * 512 + lo);
#pragma unroll
        for (int k = 0; k < 8; ++k) sum[k] += bf2f((u16)v[k]) * wv;
    }
    for (; j + 8 <= e; j += 8) {
        int4 ia = *(const int4*)&ssrc[j];
        int4 ib = *(const int4*)&ssrc[j + 4];
        float4 wa = *(const float4*)&sw[j];
        float4 wb = *(const float4*)&sw[j + 4];
        bf16x8 v0 = *(const bf16x8*)(Tg + (size_t)ia.x * 512 + lo);
        bf16x8 v1 = *(const bf16x8*)(Tg + (size_t)ia.y * 512 + lo);
        bf16x8 v2 = *(const bf16x8*)(Tg + (size_t)ia.z * 512 + lo);
        bf16x8 v3 = *(const bf16x8*)(Tg + (size_t)ia.w * 512 + lo);
        bf16x8 v4 = *(const bf16x8*)(Tg + (size_t)ib.x * 512 + lo);
        bf16x8 v5 = *(const bf16x8*)(Tg + (size_t)ib.y * 512 + lo);
        bf16x8 v6 = *(const bf16x8*)(Tg + (size_t)ib.z * 512 + lo);
        bf16x8 v7 = *(const bf16x8*)(Tg + (size_t)ib.w * 512 + lo);
#pragma unroll
        for (int k = 0; k < 8; ++k)
            sum[k] += bf2f((u16)v0[k]) * wa.x + bf2f((u16)v1[k]) * wa.y
                    + bf2f((u16)v2[k]) * wa.z + bf2f((u16)v3[k]) * wa.w
                    + bf2f((u16)v4[k]) * wb.x + bf2f((u16)v5[k]) * wb.y
                    + bf2f((u16)v6[k]) * wb.z + bf2f((u16)v7[k]) * wb.w;
    }
    for (; j + 4 <= e; j += 4) {
        int4 idx = *(const int4*)&ssrc[j];
        float4 wv = *(const float4*)&sw[j];
        bf16x8 v0 = *(const bf16x8*)(Tg + (size_t)idx.x * 512 + lo);
        bf16x8 v1 = *(const bf16x8*)(Tg + (size_t)idx.y * 512 + lo);
        bf16x8 v2 = *(const bf16x8*)(Tg + (size_t)idx.z * 512 + lo);
        bf16x8 v3 = *(const bf16x8*)(Tg + (size_t)idx.w * 512 + lo);
#pragma unroll
        for (int k = 0; k < 8; ++k)
            sum[k] += bf2f((u16)v0[k]) * wv.x + bf2f((u16)v1[k]) * wv.y
                    + bf2f((u16)v2[k]) * wv.z + bf2f((u16)v3[k]) * wv.w;
    }
    for (; j < e; ++j) {
        int idx = ssrc[j];
        float wv = sw[j];
        bf16x8 v = *(const bf16x8*)(Tg + (size_t)idx * 512 + lo);
#pragma unroll
        for (int k = 0; k < 8; ++k) sum[k] += bf2f((u16)v[k]) * wv;
    }
    size_t go = (size_t)n * 512 + lo;
    bf16x8 o;
    if (mode == 1) {
        bf16x8 xv = *(const bf16x8*)(xg + go);
#pragma unroll
        for (int k = 0; k < 8; ++k) o[k] = (short)f2bf(2.f * sum[k] - bf2f((u16)xv[k]));
    } else {
#pragma unroll
        for (int k = 0; k < 8; ++k) o[k] = (short)f2bf(sum[k]);
    }
    *(bf16x8*)(Og + go) = o;
}

// ---- fused cheb-einsum + MLP, bf16 MFMA, M=64 rows/block -----------------
// R9 structure EXACTLY (R13's bf16-residual epilogue reverted: its per-
// element 64-bit div/mod + scattered 2-B reads cost +10 µs for a traffic
// saving that never materialized). 512 thr, 8 waves, 4-deep B pipeline,
// single 33.8 KB LDS buffer, __launch_bounds__(512,6) -> 3 blocks/CU,
// occ ~50%, VGPR 40, no spill.
__global__ __launch_bounds__(512, 6) void k_fused(
        const float* __restrict__ x, const u16* __restrict__ xg,
        const u16* __restrict__ Tx1g, const u16* __restrict__ Tx2g,
        const u16* __restrict__ Wct, const float* __restrict__ bc,
        const u16* __restrict__ W1t, const float* __restrict__ b1,
        const u16* __restrict__ W2t, const float* __restrict__ b2,
        const float* __restrict__ beta, float* __restrict__ out) {
    __shared__ u16 buf[64 * 264];   // A0 (cols 0..191) -> h (0..255) -> h2
    int t = threadIdx.x;

    // stage A0 = [xg | Tx1g | Tx2g] bf16, row-major, K-stride 264
    {
        int r = t >> 3, seg = t & 7;            // 64 rows x 8 segs of 16 B
        size_t g = (size_t)blockIdx.x * 64 + r;
        int b = (int)(g / N_), n = (int)(g % N_);
        size_t go = (size_t)n * 512 + b * 64 + seg * 8;
        bf16x8 xv = *(const bf16x8*)(xg + go);
        bf16x8 t1 = *(const bf16x8*)(Tx1g + go);
        bf16x8 t2 = *(const bf16x8*)(Tx2g + go);
        *(bf16x8*)&buf[r * 264 + seg * 8] = xv;
        *(bf16x8*)&buf[r * 264 + 64 + seg * 8] = t1;
        *(bf16x8*)&buf[r * 264 + 128 + seg * 8] = t2;
    }
    __syncthreads();

    float sp = logf(1.f + expf(beta[0]));
    int lane = t & 63, w = t >> 6;
    int m = lane & 15, quad = lane >> 4;
    int q8 = quad * 8;

    // ---- GEMM1: h = A0[64x192] @ Wc[192x256], +bc, swish (regs -> buf)
    {
        f32x4 acc[4][2] = {};
        bf16x8 bfr[4][2];   // rolling 4-deep B pipeline, 2 col-tiles
        bf16x8 afr[2][4];   // A double-buffer, all 4 m-tiles
        const u16* Wp = Wct + (w * 32 + m) * 192 + q8;
#pragma unroll
        for (int d = 0; d < 4; ++d)
#pragma unroll
            for (int nt = 0; nt < 2; ++nt)
                bfr[d][nt] = *(const bf16x8*)(Wp + nt * 16 * 192 + d * 32);
#pragma unroll
        for (int r = 0; r < 4; ++r)
            afr[0][r] = *(const bf16x8*)&buf[(r * 16 + m) * 264 + q8];
#pragma unroll
        for (int kc = 0; kc < 6; ++kc) {
            if (kc < 5) {
                int koff2 = (kc + 1) * 32 + q8;
#pragma unroll
                for (int r = 0; r < 4; ++r)
                    afr[(kc + 1) & 1][r] = *(const bf16x8*)&buf[(r * 16 + m) * 264 + koff2];
            }
#pragma unroll
            for (int nt = 0; nt < 2; ++nt) {
                acc[0][nt] = MFMA16(afr[kc & 1][0], bfr[kc & 3][nt], acc[0][nt]);
                acc[1][nt] = MFMA16(afr[kc & 1][1], bfr[kc & 3][nt], acc[1][nt]);
                acc[2][nt] = MFMA16(afr[kc & 1][2], bfr[kc & 3][nt], acc[2][nt]);
                acc[3][nt] = MFMA16(afr[kc & 1][3], bfr[kc & 3][nt], acc[3][nt]);
            }
            if (kc + 4 < 6) {
#pragma unroll
                for (int nt = 0; nt < 2; ++nt)
                    bfr[kc & 3][nt] = *(const bf16x8*)(Wp + nt * 16 * 192 + (kc + 4) * 32);
            }
        }
        __syncthreads();   // all waves done reading A0; safe to overwrite
#pragma unroll
        for (int mt = 0; mt < 4; ++mt)
#pragma unroll
            for (int nt = 0; nt < 2; ++nt) {
                int col = w * 32 + nt * 16 + m;
                float bcv = bc[col];
#pragma unroll
                for (int i = 0; i < 4; ++i) {
                    int row = mt * 16 + quad * 4 + i;
                    buf[row * 264 + col] = f2bf(swish_f(acc[mt][nt][i] + bcv, sp));
                }
            }
    }
    __syncthreads();

    // ---- GEMM2: h2 = A1[64x256] @ W1[256x256], +b1, swish (regs -> buf)
    {
        f32x4 acc[4][2] = {};
        bf16x8 bfr[4][2];
        bf16x8 afr[2][4];
        const u16* Wp = W1t + (w * 32 + m) * 256 + q8;
#pragma unroll
        for (int d = 0; d < 4; ++d)
#pragma unroll
            for (int nt = 0; nt < 2; ++nt)
                bfr[d][nt] = *(const bf16x8*)(Wp + nt * 16 * 256 + d * 32);
#pragma unroll
        for (int r = 0; r < 4; ++r)
            afr[0][r] = *(const bf16x8*)&buf[(r * 16 + m) * 264 + q8];
#pragma unroll
        for (int kc = 0; kc < 8; ++kc) {
            if (kc < 7) {
                int koff2 = (kc + 1) * 32 + q8;
#pragma unroll
                for (int r = 0; r < 4; ++r)
                    afr[(kc + 1) & 1][r] = *(const bf16x8*)&buf[(r * 16 + m) * 264 + koff2];
            }
#pragma unroll
            for (int nt = 0; nt < 2; ++nt) {
                acc[0][nt] = MFMA16(afr[kc & 1][0], bfr[kc & 3][nt], acc[0][nt]);
                acc[1][nt] = MFMA16(afr[kc & 1][1], bfr[kc & 3][nt], acc[1][nt]);
                acc[2][nt] = MFMA16(afr[kc & 1][2], bfr[kc & 3][nt], acc[2][nt]);
                acc[3][nt] = MFMA16(afr[kc & 1][3], bfr[kc & 3][nt], acc[3][nt]);
            }
            if (kc + 4 < 8) {
#pragma unroll
                for (int nt = 0; nt < 2; ++nt)
                    bfr[kc & 3][nt] = *(const bf16x8*)(Wp + nt * 16 * 256 + (kc + 4) * 32);
            }
        }
        __syncthreads();   // all waves done reading h; safe to overwrite
#pragma unroll
        for (int mt = 0; mt < 4; ++mt)
#pragma unroll
            for (int nt = 0; nt < 2; ++nt) {
                int col = w * 32 + nt * 16 + m;
                float b1v = b1[col];
#pragma unroll
                for (int i = 0; i < 4; ++i) {
                    int row = mt * 16 + quad * 4 + i;
                    buf[row * 264 + col] = f2bf(swish_f(acc[mt][nt][i] + b1v, sp));
                }
            }
    }
    __syncthreads();

    // ---- GEMM3: Fx = A2[64x256] @ W2[256x64], +b2; out = Fx + x, Fx
    // wave (wm3 = w>>2, wn3 = w&3): rows wm3*32..+32, cols wn3*16..+16
    {
        int wm3 = w >> 2, wn3 = w & 3;
        int rb3 = wm3 * 32;
        f32x4 acc3[2] = {};
        bf16x8 bfr[8];      // whole B panel preloaded (8 x 16B = 32 VGPR)
        bf16x8 afr[2][2];
        const u16* Wp = W2t + (wn3 * 16 + m) * 256 + q8;
#pragma unroll
        for (int d = 0; d < 8; ++d) bfr[d] = *(const bf16x8*)(Wp + d * 32);
#pragma unroll
        for (int r = 0; r < 2; ++r)
            afr[0][r] = *(const bf16x8*)&buf[(rb3 + r * 16 + m) * 264 + q8];
#pragma unroll
        for (int kc = 0; kc < 8; ++kc) {
            if (kc < 7) {
                int koff2 = (kc + 1) * 32 + q8;
#pragma unroll
                for (int r = 0; r < 2; ++r)
                    afr[(kc + 1) & 1][r] = *(const bf16x8*)&buf[(rb3 + r * 16 + m) * 264 + koff2];
            }
            acc3[0] = MFMA16(afr[kc & 1][0], bfr[kc], acc3[0]);
            acc3[1] = MFMA16(afr[kc & 1][1], bfr[kc], acc3[1]);
        }
        int col = wn3 * 16 + m;
        float b2v = b2[col];
#pragma unroll
        for (int mt = 0; mt < 2; ++mt)
#pragma unroll
            for (int i = 0; i < 4; ++i) {
                int row = rb3 + mt * 16 + quad * 4 + i;
                size_t g = ((size_t)blockIdx.x * 64 + row) * 64 + col;
                float f = acc3[mt][i] + b2v;
                out[g] = f + x[g];
                out[OUT_OFF_ + g] = f;
            }
    }
}

extern "C" void kernel_launch(void* const* d_in, const int* in_sizes, int n_in,
                              void* d_out, int out_size, void* d_ws, size_t ws_size,
                              hipStream_t stream) {
    const float* x    = (const float*)d_in[0];
    const float* ew   = (const float*)d_in[1];
    const float* Wc   = (const float*)d_in[2];
    const float* bc   = (const float*)d_in[3];
    const float* W1   = (const float*)d_in[4];
    const float* b1   = (const float*)d_in[5];
    const float* W2   = (const float*)d_in[6];
    const float* b2   = (const float*)d_in[7];
    const float* beta = (const float*)d_in[8];
    const int*   ei   = (const int*)d_in[9];
    const int* src = ei;
    const int* dst = ei + E_;
    float* out = (float*)d_out;

    // workspace layout (float units) — deg|cnt10 contiguous for one memset
    float* ws = (float*)d_ws;
    float* deg      = ws + 0;                 // N floats
    int*   cnt10    = (int*)(ws + 10000);     // N*10 ints (400 KB)
    float* dis      = ws + 110000;            // N
    int*   offs     = (int*)(ws + 120000);    // N+1 (pad to 10008)
    int*   cursor10 = (int*)(ws + 130008);    // N*10 ints
    int*   ssrc     = (int*)(ws + 230008);    // E
    float* sw       = ws + 390008;            // E
    u16*   xg       = (u16*)(ws + 550008);    // [n][b][c] B*N*C u16
    u16*   Tx1g     = (u16*)(ws + 3110008);   // [n][b][c] B*N*C u16
    u16*   Tx2g     = (u16*)(ws + 5670008);   // [n][b][c] B*N*C u16
    u16*   Wct      = (u16*)(ws + 8230008);   // 49152 u16
    u16*   W1t      = (u16*)(ws + 8254584);   // 65536 u16
    u16*   W2t      = (u16*)(ws + 8287352);   // 16384 u16

    hipMemsetAsync(deg, 0, (size_t)(10000 + 100000) * 4, stream);  // deg+cnt10

    k_deg<<<(E_ + 255) / 256, 256, 0, stream>>>(src, dst, ew, deg, cnt10);
    k_scan<<<1, 1024, 0, stream>>>(cnt10, deg, offs, cursor10, dis);
    k_sp<<<SCAT_BLKS_ + (131072 + (B_ * N_ * C_) / 4) / 256, 256, 0, stream>>>(
        src, dst, ew, dis, cursor10, ssrc, sw, Wc, W1, W2, x, Wct, W1t, W2t, xg);
    k_prop_g<<<N_ / 4, 256, 0, stream>>>(xg, offs, ssrc, sw, xg, Tx1g, 0);
    k_prop_g<<<N_ / 4, 256, 0, stream>>>(Tx1g, offs, ssrc, sw, xg, Tx2g, 1);
    k_fused<<<ROWS_ / 64, 512, 0, stream>>>(x, xg, Tx1g, Tx2g, Wct, bc, W1t, b1,
                                            W2t, b2, beta, out);
}

// Round 15
// 241.883 us; speedup vs baseline: 1.1412x; 1.1412x over previous
//
#include <hip/hip_runtime.h>
#include <cstdint>
#include <cstddef>

#define B_ 8
#define N_ 10000
#define C_ 64
#define DIM_ 256
#define E_ 160000
#define ROWS_ (B_ * N_)            // 80000
#define OUT_OFF_ ((size_t)B_ * N_ * C_)  // 5,120,000

typedef unsigned short u16;
typedef unsigned int u32;
typedef __attribute__((ext_vector_type(8))) short bf16x8;
typedef __attribute__((ext_vector_type(4))) float f32x4;

__device__ __forceinline__ u16 f2bf(float f) {
    unsigned int u = __float_as_uint(f);
    unsigned int r = u + 0x7FFF + ((u >> 16) & 1);  // RNE
    return (u16)(r >> 16);
}
__device__ __forceinline__ float bf2f(u32 h) {      // low 16 bits hold bf16
    return __uint_as_float(h << 16);
}
__device__ __forceinline__ unsigned int pack2(float a, float b) {
    return (unsigned int)f2bf(a) | ((unsigned int)f2bf(b) << 16);
}
__device__ __forceinline__ float swish_f(float v, float sp) {
    float e = __expf(-v * sp);
    float s = __builtin_amdgcn_rcpf(1.0f + e);
    return v * s * (1.0f / 1.1f);
}

#define MFMA16(a, b, c) __builtin_amdgcn_mfma_f32_16x16x32_bf16(a, b, c, 0, 0, 0)

// ---- graph preprocessing -------------------------------------------------
// R15: exact R9 configuration (best measured total, 241.7 µs). R14's
// src-chunk sorting reverted: avg degree 16 -> ~1.6 edges/chunk/node, no
// temporal window forms; and R11's measured ~70 MB HBM fetch/pass is already
// at the 8-XCD minimum (8 x 10.2 MB source copies) — no L2 headroom exists.

__global__ void k_deg(const int* __restrict__ dst, const float* __restrict__ ew,
                      float* __restrict__ deg, int* __restrict__ cnt) {
    int e = blockIdx.x * 256 + threadIdx.x;
    if (e < E_) {
        int d = dst[e];
        atomicAdd(&deg[d], ew[e]);
        atomicAdd(&cnt[d], 1);
    }
}

// scan + dis fused (R9). Single 1024-thread block, CH=10 elems/thread.
__global__ void k_scan(const int* __restrict__ cnt, const float* __restrict__ deg,
                       int* __restrict__ offs, int* __restrict__ cursor,
                       float* __restrict__ dis) {
    __shared__ int part[1024];
    int t = threadIdx.x;
    const int CH = 10;
    int base = t * CH;
    int s = 0;
    for (int i = 0; i < CH; i++) {
        int idx = base + i;
        if (idx < N_) s += cnt[idx];
    }
    part[t] = s;
    __syncthreads();
    for (int off = 1; off < 1024; off <<= 1) {
        int v = 0;
        if (t >= off) v = part[t - off];
        __syncthreads();
        if (t >= off) part[t] += v;
        __syncthreads();
    }
    int run = (t > 0) ? part[t - 1] : 0;
    for (int i = 0; i < CH; i++) {
        int idx = base + i;
        if (idx < N_) {
            offs[idx] = run;
            cursor[idx] = run;
            run += cnt[idx];
            float d = deg[idx];
            dis[idx] = d > 0.f ? rsqrtf(d) : 0.f;
        }
    }
    if (t == 1023) offs[N_] = run;
}

// scatter + weight-prep merged (R9); block-range split.
#define SCAT_BLKS_ ((E_ + 255) / 256)              // 625
__global__ void k_sp(const int* __restrict__ src, const int* __restrict__ dst,
                     const float* __restrict__ ew, const float* __restrict__ dis,
                     int* __restrict__ cursor, int* __restrict__ ssrc,
                     float* __restrict__ sw,
                     const float* __restrict__ Wc, const float* __restrict__ W1,
                     const float* __restrict__ W2, const float* __restrict__ x,
                     u16* __restrict__ Wct, u16* __restrict__ W1t,
                     u16* __restrict__ W2t, u16* __restrict__ xg) {
    if (blockIdx.x < SCAT_BLKS_) {
        int e = blockIdx.x * 256 + threadIdx.x;
        if (e < E_) {
            int sn = src[e], dn = dst[e];
            float w = -(dis[sn] * ew[e] * dis[dn]);
            int p = atomicAdd(&cursor[dn], 1);
            ssrc[p] = sn;
            sw[p] = w;
        }
        return;
    }
    int i = (blockIdx.x - SCAT_BLKS_) * 256 + threadIdx.x;
    if (i < 49152) {
        int nr = i / 192, k = i % 192;
        Wct[i] = f2bf(Wc[k * 256 + nr]);
    } else if (i < 114688) {
        int j = i - 49152;
        int nr = j >> 8, k = j & 255;
        W1t[j] = f2bf(W1[k * 256 + nr]);
    } else if (i < 131072) {
        int j = i - 114688;
        int nr = j >> 8, k = j & 255;
        W2t[j] = f2bf(W2[k * 64 + nr]);
    } else {
        int j = i - 131072;
        if (j < (B_ * N_ * C_) / 4) {
            float4 v = ((const float4*)x)[j];
            int flat4 = j * 4;                 // [b][n][c] flat f32 index
            int b = flat4 / (N_ * C_);
            int rem = flat4 - b * (N_ * C_);
            int n = rem >> 6, c = rem & 63;
            uint2 pv = {pack2(v.x, v.y), pack2(v.z, v.w)};
            *(uint2*)(xg + (size_t)n * 512 + b * 64 + c) = pv;
        }
    }
}

// Batch-merged gather SpMM (R7/R8/R9 — best measured: 26 µs/pass, at the
// 8-XCD fetch floor). One wave per NODE; per edge one contiguous 1 KB row
// (8 batches x 64 ch), 8-deep edge pipeline. Lane l owns
// (b=l>>3, c=(l&7)*8..+8). mode==1: O = 2*sum - xg_row (fused Tx2).
__global__ __launch_bounds__(256) void k_prop_g(
        const u16* __restrict__ Tg, const int* __restrict__ offs,
        const int* __restrict__ ssrc, const float* __restrict__ sw,
        const u16* __restrict__ xg, u16* __restrict__ Og, int mode) {
    int w = __builtin_amdgcn_readfirstlane(threadIdx.x >> 6);
    int lane = threadIdx.x & 63;
    int n = blockIdx.x * 4 + w;
    int s = offs[n], e = offs[n + 1];
    int lo = lane * 8;
    float sum[8] = {};
    int j = s;
    for (; j < e && (j & 3); ++j) {
        int idx = ssrc[j];
        float wv = sw[j];
        bf16x8 v = *(const bf16x8*)(Tg + (size_t)idx * 512 + lo);
#pragma unroll
        for (int k = 0; k < 8; ++k) sum[k] += bf2f((u16)v[k]) * wv;
    }
    for (; j + 8 <= e; j += 8) {
        int4 ia = *(const int4*)&ssrc[j];
        int4 ib = *(const int4*)&ssrc[j + 4];
        float4 wa = *(const float4*)&sw[j];
        float4 wb = *(const float4*)&sw[j + 4];
        bf16x8 v0 = *(const bf16x8*)(Tg + (size_t)ia.x * 512 + lo);
        bf16x8 v1 = *(const bf16x8*)(Tg + (size_t)ia.y * 512 + lo);
        bf16x8 v2 = *(const bf16x8*)(Tg + (size_t)ia.z * 512 + lo);
        bf16x8 v3 = *(const bf16x8*)(Tg + (size_t)ia.w * 512 + lo);
        bf16x8 v4 = *(const bf16x8*)(Tg + (size_t)ib.x * 512 + lo);
        bf16x8 v5 = *(const bf16x8*)(Tg + (size_t)ib.y * 512 + lo);
        bf16x8 v6 = *(const bf16x8*)(Tg + (size_t)ib.z * 512 + lo);
        bf16x8 v7 = *(const bf16x8*)(Tg + (size_t)ib.w * 512 + lo);
#pragma unroll
        for (int k = 0; k < 8; ++k)
            sum[k] += bf2f((u16)v0[k]) * wa.x + bf2f((u16)v1[k]) * wa.y
                    + bf2f((u16)v2[k]) * wa.z + bf2f((u16)v3[k]) * wa.w
                    + bf2f((u16)v4[k]) * wb.x + bf2f((u16)v5[k]) * wb.y
                    + bf2f((u16)v6[k]) * wb.z + bf2f((u16)v7[k]) * wb.w;
    }
    for (; j + 4 <= e; j += 4) {
        int4 idx = *(const int4*)&ssrc[j];
        float4 wv = *(const float4*)&sw[j];
        bf16x8 v0 = *(const bf16x8*)(Tg + (size_t)idx.x * 512 + lo);
        bf16x8 v1 = *(const bf16x8*)(Tg + (size_t)idx.y * 512 + lo);
        bf16x8 v2 = *(const bf16x8*)(Tg + (size_t)idx.z * 512 + lo);
        bf16x8 v3 = *(const bf16x8*)(Tg + (size_t)idx.w * 512 + lo);
#pragma unroll
        for (int k = 0; k < 8; ++k)
            sum[k] += bf2f((u16)v0[k]) * wv.x + bf2f((u16)v1[k]) * wv.y
                    + bf2f((u16)v2[k]) * wv.z + bf2f((u16)v3[k]) * wv.w;
    }
    for (; j < e; ++j) {
        int idx = ssrc[j];
        float wv = sw[j];
        bf16x8 v = *(const bf16x8*)(Tg + (size_t)idx * 512 + lo);
#pragma unroll
        for (int k = 0; k < 8; ++k) sum[k] += bf2f((u16)v[k]) * wv;
    }
    size_t go = (size_t)n * 512 + lo;
    bf16x8 o;
    if (mode == 1) {
        bf16x8 xv = *(const bf16x8*)(xg + go);
#pragma unroll
        for (int k = 0; k < 8; ++k) o[k] = (short)f2bf(2.f * sum[k] - bf2f((u16)xv[k]));
    } else {
#pragma unroll
        for (int k = 0; k < 8; ++k) o[k] = (short)f2bf(sum[k]);
    }
    *(bf16x8*)(Og + go) = o;
}

// ---- fused cheb-einsum + MLP, bf16 MFMA, M=64 rows/block -----------------
// R9 structure EXACTLY (best measured: 61 µs). 512 thr, 8 waves (32-col
// N-slices for GEMM1/2; 32x16 for GEMM3), 4-deep B pipeline, single
// 33.8 KB LDS buffer, __launch_bounds__(512,6) -> 3 blocks/CU, occ ~50%,
// VGPR 40, no spill. Epilogue residual reads linear f32 x (R13's bf16-xg
// variant cost +10 µs in div/mod + scattered reads for no traffic saving).
__global__ __launch_bounds__(512, 6) void k_fused(
        const float* __restrict__ x, const u16* __restrict__ xg,
        const u16* __restrict__ Tx1g, const u16* __restrict__ Tx2g,
        const u16* __restrict__ Wct, const float* __restrict__ bc,
        const u16* __restrict__ W1t, const float* __restrict__ b1,
        const u16* __restrict__ W2t, const float* __restrict__ b2,
        const float* __restrict__ beta, float* __restrict__ out) {
    __shared__ u16 buf[64 * 264];   // A0 (cols 0..191) -> h (0..255) -> h2
    int t = threadIdx.x;

    // stage A0 = [xg | Tx1g | Tx2g] bf16, row-major, K-stride 264
    {
        int r = t >> 3, seg = t & 7;            // 64 rows x 8 segs of 16 B
        size_t g = (size_t)blockIdx.x * 64 + r;
        int b = (int)(g / N_), n = (int)(g % N_);
        size_t go = (size_t)n * 512 + b * 64 + seg * 8;
        bf16x8 xv = *(const bf16x8*)(xg + go);
        bf16x8 t1 = *(const bf16x8*)(Tx1g + go);
        bf16x8 t2 = *(const bf16x8*)(Tx2g + go);
        *(bf16x8*)&buf[r * 264 + seg * 8] = xv;
        *(bf16x8*)&buf[r * 264 + 64 + seg * 8] = t1;
        *(bf16x8*)&buf[r * 264 + 128 + seg * 8] = t2;
    }
    __syncthreads();

    float sp = logf(1.f + expf(beta[0]));
    int lane = t & 63, w = t >> 6;
    int m = lane & 15, quad = lane >> 4;
    int q8 = quad * 8;

    // ---- GEMM1: h = A0[64x192] @ Wc[192x256], +bc, swish (regs -> buf)
    {
        f32x4 acc[4][2] = {};
        bf16x8 bfr[4][2];   // rolling 4-deep B pipeline, 2 col-tiles
        bf16x8 afr[2][4];   // A double-buffer, all 4 m-tiles
        const u16* Wp = Wct + (w * 32 + m) * 192 + q8;
#pragma unroll
        for (int d = 0; d < 4; ++d)
#pragma unroll
            for (int nt = 0; nt < 2; ++nt)
                bfr[d][nt] = *(const bf16x8*)(Wp + nt * 16 * 192 + d * 32);
#pragma unroll
        for (int r = 0; r < 4; ++r)
            afr[0][r] = *(const bf16x8*)&buf[(r * 16 + m) * 264 + q8];
#pragma unroll
        for (int kc = 0; kc < 6; ++kc) {
            if (kc < 5) {
                int koff2 = (kc + 1) * 32 + q8;
#pragma unroll
                for (int r = 0; r < 4; ++r)
                    afr[(kc + 1) & 1][r] = *(const bf16x8*)&buf[(r * 16 + m) * 264 + koff2];
            }
#pragma unroll
            for (int nt = 0; nt < 2; ++nt) {
                acc[0][nt] = MFMA16(afr[kc & 1][0], bfr[kc & 3][nt], acc[0][nt]);
                acc[1][nt] = MFMA16(afr[kc & 1][1], bfr[kc & 3][nt], acc[1][nt]);
                acc[2][nt] = MFMA16(afr[kc & 1][2], bfr[kc & 3][nt], acc[2][nt]);
                acc[3][nt] = MFMA16(afr[kc & 1][3], bfr[kc & 3][nt], acc[3][nt]);
            }
            if (kc + 4 < 6) {
#pragma unroll
                for (int nt = 0; nt < 2; ++nt)
                    bfr[kc & 3][nt] = *(const bf16x8*)(Wp + nt * 16 * 192 + (kc + 4) * 32);
            }
        }
        __syncthreads();   // all waves done reading A0; safe to overwrite
#pragma unroll
        for (int mt = 0; mt < 4; ++mt)
#pragma unroll
            for (int nt = 0; nt < 2; ++nt) {
                int col = w * 32 + nt * 16 + m;
                float bcv = bc[col];
#pragma unroll
                for (int i = 0; i < 4; ++i) {
                    int row = mt * 16 + quad * 4 + i;
                    buf[row * 264 + col] = f2bf(swish_f(acc[mt][nt][i] + bcv, sp));
                }
            }
    }
    __syncthreads();

    // ---- GEMM2: h2 = A1[64x256] @ W1[256x256], +b1, swish (regs -> buf)
    {
        f32x4 acc[4][2] = {};
        bf16x8 bfr[4][2];
        bf16x8 afr[2][4];
        const u16* Wp = W1t + (w * 32 + m) * 256 + q8;
#pragma unroll
        for (int d = 0; d < 4; ++d)
#pragma unroll
            for (int nt = 0; nt < 2; ++nt)
                bfr[d][nt] = *(const bf16x8*)(Wp + nt * 16 * 256 + d * 32);
#pragma unroll
        for (int r = 0; r < 4; ++r)
            afr[0][r] = *(const bf16x8*)&buf[(r * 16 + m) * 264 + q8];
#pragma unroll
        for (int kc = 0; kc < 8; ++kc) {
            if (kc < 7) {
                int koff2 = (kc + 1) * 32 + q8;
#pragma unroll
                for (int r = 0; r < 4; ++r)
                    afr[(kc + 1) & 1][r] = *(const bf16x8*)&buf[(r * 16 + m) * 264 + koff2];
            }
#pragma unroll
            for (int nt = 0; nt < 2; ++nt) {
                acc[0][nt] = MFMA16(afr[kc & 1][0], bfr[kc & 3][nt], acc[0][nt]);
                acc[1][nt] = MFMA16(afr[kc & 1][1], bfr[kc & 3][nt], acc[1][nt]);
                acc[2][nt] = MFMA16(afr[kc & 1][2], bfr[kc & 3][nt], acc[2][nt]);
                acc[3][nt] = MFMA16(afr[kc & 1][3], bfr[kc & 3][nt], acc[3][nt]);
            }
            if (kc + 4 < 8) {
#pragma unroll
                for (int nt = 0; nt < 2; ++nt)
                    bfr[kc & 3][nt] = *(const bf16x8*)(Wp + nt * 16 * 256 + (kc + 4) * 32);
            }
        }
        __syncthreads();   // all waves done reading h; safe to overwrite
#pragma unroll
        for (int mt = 0; mt < 4; ++mt)
#pragma unroll
            for (int nt = 0; nt < 2; ++nt) {
                int col = w * 32 + nt * 16 + m;
                float b1v = b1[col];
#pragma unroll
                for (int i = 0; i < 4; ++i) {
                    int row = mt * 16 + quad * 4 + i;
                    buf[row * 264 + col] = f2bf(swish_f(acc[mt][nt][i] + b1v, sp));
                }
            }
    }
    __syncthreads();

    // ---- GEMM3: Fx = A2[64x256] @ W2[256x64], +b2; out = Fx + x, Fx
    // wave (wm3 = w>>2, wn3 = w&3): rows wm3*32..+32, cols wn3*16..+16
    {
        int wm3 = w >> 2, wn3 = w & 3;
        int rb3 = wm3 * 32;
        f32x4 acc3[2] = {};
        bf16x8 bfr[8];      // whole B panel preloaded (8 x 16B = 32 VGPR)
        bf16x8 afr[2][2];
        const u16* Wp = W2t + (wn3 * 16 + m) * 256 + q8;
#pragma unroll
        for (int d = 0; d < 8; ++d) bfr[d] = *(const bf16x8*)(Wp + d * 32);
#pragma unroll
        for (int r = 0; r < 2; ++r)
            afr[0][r] = *(const bf16x8*)&buf[(rb3 + r * 16 + m) * 264 + q8];
#pragma unroll
        for (int kc = 0; kc < 8; ++kc) {
            if (kc < 7) {
                int koff2 = (kc + 1) * 32 + q8;
#pragma unroll
                for (int r = 0; r < 2; ++r)
                    afr[(kc + 1) & 1][r] = *(const bf16x8*)&buf[(rb3 + r * 16 + m) * 264 + koff2];
            }
            acc3[0] = MFMA16(afr[kc & 1][0], bfr[kc], acc3[0]);
            acc3[1] = MFMA16(afr[kc & 1][1], bfr[kc], acc3[1]);
        }
        int col = wn3 * 16 + m;
        float b2v = b2[col];
#pragma unroll
        for (int mt = 0; mt < 2; ++mt)
#pragma unroll
            for (int i = 0; i < 4; ++i) {
                int row = rb3 + mt * 16 + quad * 4 + i;
                size_t g = ((size_t)blockIdx.x * 64 + row) * 64 + col;
                float f = acc3[mt][i] + b2v;
                out[g] = f + x[g];
                out[OUT_OFF_ + g] = f;
            }
    }
}

extern "C" void kernel_launch(void* const* d_in, const int* in_sizes, int n_in,
                              void* d_out, int out_size, void* d_ws, size_t ws_size,
                              hipStream_t stream) {
    const float* x    = (const float*)d_in[0];
    const float* ew   = (const float*)d_in[1];
    const float* Wc   = (const float*)d_in[2];
    const float* bc   = (const float*)d_in[3];
    const float* W1   = (const float*)d_in[4];
    const float* b1   = (const float*)d_in[5];
    const float* W2   = (const float*)d_in[6];
    const float* b2   = (const float*)d_in[7];
    const float* beta = (const float*)d_in[8];
    const int*   ei   = (const int*)d_in[9];
    const int* src = ei;
    const int* dst = ei + E_;
    float* out = (float*)d_out;

    // workspace layout (float units) — deg|cnt contiguous for single memset
    float* ws = (float*)d_ws;
    float* deg    = ws + 0;                 // N
    int*   cnt    = (int*)(ws + 10000);     // N  (contiguous with deg)
    float* dis    = ws + 20000;             // N
    int*   offs   = (int*)(ws + 30000);     // N+1 (pad to 10008)
    int*   cursor = (int*)(ws + 40008);     // N
    int*   ssrc   = (int*)(ws + 50008);     // E
    float* sw     = ws + 210008;            // E
    u16*   xg     = (u16*)(ws + 370008);    // [n][b][c] B*N*C u16
    u16*   Tx1g   = (u16*)(ws + 2930008);   // [n][b][c] B*N*C u16
    u16*   Tx2g   = (u16*)(ws + 5490008);   // [n][b][c] B*N*C u16
    u16*   Wct    = (u16*)(ws + 8050008);   // 49152 u16
    u16*   W1t    = (u16*)(ws + 8074584);   // 65536 u16
    u16*   W2t    = (u16*)(ws + 8107352);   // 16384 u16

    hipMemsetAsync(deg, 0, (size_t)2 * N_ * sizeof(float), stream);  // deg+cnt

    k_deg<<<(E_ + 255) / 256, 256, 0, stream>>>(dst, ew, deg, cnt);
    k_scan<<<1, 1024, 0, stream>>>(cnt, deg, offs, cursor, dis);
    k_sp<<<SCAT_BLKS_ + (131072 + (B_ * N_ * C_) / 4) / 256, 256, 0, stream>>>(
        src, dst, ew, dis, cursor, ssrc, sw, Wc, W1, W2, x, Wct, W1t, W2t, xg);
    k_prop_g<<<N_ / 4, 256, 0, stream>>>(xg, offs, ssrc, sw, xg, Tx1g, 0);
    k_prop_g<<<N_ / 4, 256, 0, stream>>>(Tx1g, offs, ssrc, sw, xg, Tx2g, 1);
    k_fused<<<ROWS_ / 64, 512, 0, stream>>>(x, xg, Tx1g, Tx2g, Wct, bc, W1t, b1,
                                            W2t, b2, beta, out);
}